// Round 1
// baseline (762.281 us; speedup 1.0000x reference)
//
#include <hip/hip_runtime.h>
#include <math.h>

#define NB 4
#define SS 200
#define LT 256
#define DD 256
#define NH 8
#define NLAYER 2
#define FFD 1024
#define BERTD 768
#define CIN 868
#define NEGINF -1e15f

// ---------------- embedding: x = (raw_char@Wc+bc)*char_mask + (raw@Wl+bl)*lex_mask ----
__global__ void embed_kernel(const int* __restrict__ lattice, const int* __restrict__ bigrams,
                             const int* __restrict__ seq_len, const int* __restrict__ lex_num,
                             const float* __restrict__ bert, const float* __restrict__ lat_t,
                             const float* __restrict__ big_t,
                             const float* __restrict__ Wc, const float* __restrict__ bc,
                             const float* __restrict__ Wl, const float* __restrict__ bl,
                             float* __restrict__ x)
{
    __shared__ float rc[8][872];           // 8 rows of raw_char[868]
    const int t = threadIdx.x;
    const int row0 = blockIdx.x * 8;       // row = b*LT + l
    for (int r = 0; r < 8; ++r) {
        int row = row0 + r;
        int b = row >> 8, l = row & 255;
        int lat = lattice[row];
        int big = (l < SS) ? bigrams[b*SS + l] : 0;
        for (int i = t; i < CIN; i += 256) {
            float v;
            if (i < 50)        v = lat_t[lat*50 + i];
            else if (i < 100)  v = (l < SS) ? big_t[big*50 + (i-50)] : 0.f;
            else               v = (l < SS) ? bert[(b*SS + l)*BERTD + (i-100)] : 0.f;
            rc[r][i] = v;
        }
    }
    __syncthreads();
    float accC[8], accL[8];
    const float bcv = bc[t], blv = bl[t];
    #pragma unroll
    for (int r = 0; r < 8; ++r) { accC[r] = bcv; accL[r] = blv; }
    for (int i = 0; i < 50; ++i) {         // raw part feeds both projections
        float wc = Wc[i*DD + t], wl = Wl[i*DD + t];
        #pragma unroll
        for (int r = 0; r < 8; ++r) { float v = rc[r][i]; accC[r] += v*wc; accL[r] += v*wl; }
    }
    for (int i = 50; i < CIN; ++i) {
        float wc = Wc[i*DD + t];
        #pragma unroll
        for (int r = 0; r < 8; ++r) accC[r] += rc[r][i]*wc;
    }
    for (int r = 0; r < 8; ++r) {
        int row = row0 + r;
        int b = row >> 8, l = row & 255;
        int sl = seq_len[b], tl = sl + lex_num[b];
        x[row*DD + t] = (l < sl) ? accC[r] : ((l < tl) ? accL[r] : 0.f);
    }
}

// ---------------- T[k][p][o] = pe[p] @ W_fus[k]  (b_fus folded into k==0) -------------
__global__ void build_T(const float* __restrict__ W_fus, const float* __restrict__ b_fus,
                        float* __restrict__ T)
{
    __shared__ float pe[4][256];
    const int t = threadIdx.x, k = blockIdx.y;
    const int p0 = blockIdx.x * 4;
    const float fr = expf(-(float)(t & 127) * (9.210340371976184f / 127.0f));
    #pragma unroll
    for (int i = 0; i < 4; ++i) {
        int p = p0 + i;
        float arg = (float)(p > 1024 ? 0 : p) * fr;
        pe[i][t] = (t < 128) ? sinf(arg) : cosf(arg);
    }
    __syncthreads();
    float acc[4];
    const float bias = (k == 0) ? b_fus[t] : 0.f;
    #pragma unroll
    for (int i = 0; i < 4; ++i) acc[i] = bias;
    const float* W = W_fus + k * DD * DD;
    for (int e = 0; e < DD; ++e) {
        float w = W[e*DD + t];
        #pragma unroll
        for (int i = 0; i < 4; ++i) acc[i] += pe[i][e] * w;
    }
    #pragma unroll
    for (int i = 0; i < 4; ++i) {
        int p = p0 + i;
        if (p <= 1024) T[(k*1025 + p)*DD + t] = acc[i];
    }
}

// ---------------- WrT[l][j][e] = Wr[l][e][j] ------------------------------------------
__global__ void transpose_wr(const float* __restrict__ Wr, float* __restrict__ WrT)
{
    const int j = blockIdx.x & 255, l = blockIdx.x >> 8, e = threadIdx.x;
    WrT[(l*DD + j)*DD + e] = Wr[l*DD*DD + e*DD + j];
}

// ---------------- generic f32 GEMM: C = (A@W + bias [+ resid]) [relu] -----------------
template<bool RELU>
__global__ void gemm32(const float* __restrict__ A, const float* __restrict__ W,
                       const float* __restrict__ bias, const float* __restrict__ resid,
                       float* __restrict__ C, int M, int N, int K)
{
    __shared__ float As[32][36];
    __shared__ float Bs[32][36];
    const int t = threadIdx.x;
    const int row0 = blockIdx.y * 32, col0 = blockIdx.x * 32;
    const int tr = t >> 4, tc = t & 15;
    const int lr = t >> 3, lc4 = (t & 7) * 4;
    float a00 = 0.f, a01 = 0.f, a10 = 0.f, a11 = 0.f;
    for (int k0 = 0; k0 < K; k0 += 32) {
        float4 av = *(const float4*)&A[(row0 + lr)*K + k0 + lc4];
        float4 bv = *(const float4*)&W[(k0 + lr)*N + col0 + lc4];
        *(float4*)&As[lr][lc4] = av;
        *(float4*)&Bs[lr][lc4] = bv;
        __syncthreads();
        #pragma unroll
        for (int kk = 0; kk < 32; ++kk) {
            float x0 = As[2*tr][kk], x1 = As[2*tr+1][kk];
            float2 bb = *(const float2*)&Bs[kk][2*tc];
            a00 += x0*bb.x; a01 += x0*bb.y; a10 += x1*bb.x; a11 += x1*bb.y;
        }
        __syncthreads();
    }
    const int r0 = row0 + 2*tr, c0 = col0 + 2*tc;
    float b0 = bias ? bias[c0] : 0.f, b1 = bias ? bias[c0+1] : 0.f;
    float v00 = a00 + b0, v01 = a01 + b1, v10 = a10 + b0, v11 = a11 + b1;
    if (resid) {
        v00 += resid[r0*N + c0];     v01 += resid[r0*N + c0 + 1];
        v10 += resid[(r0+1)*N + c0]; v11 += resid[(r0+1)*N + c0 + 1];
    }
    if (RELU) {
        v00 = fmaxf(v00, 0.f); v01 = fmaxf(v01, 0.f);
        v10 = fmaxf(v10, 0.f); v11 = fmaxf(v11, 0.f);
    }
    C[r0*N + c0]     = v00; C[r0*N + c0 + 1]     = v01;
    C[(r0+1)*N + c0] = v10; C[(r0+1)*N + c0 + 1] = v11;
}

// ---------------- qr[b,q,h,e] = sum_d (Q[b,q,h*32+d]+vb[h*32+d]) * WrT[h*32+d][e] -----
__global__ void qr_kernel(const float* __restrict__ qbuf, const float* __restrict__ vb,
                          const float* __restrict__ WrT, float* __restrict__ qr)
{
    __shared__ float qv[256];
    const int t = threadIdx.x, row = blockIdx.x;          // b*LT + q
    qv[t] = qbuf[row*DD + t] + vb[t];
    __syncthreads();
    #pragma unroll
    for (int h = 0; h < NH; ++h) {
        float acc = 0.f;
        const float* wt = WrT + (h*32)*DD;
        #pragma unroll 8
        for (int d = 0; d < 32; ++d)
            acc += qv[h*32 + d] * wt[d*DD + t];
        qr[(row*NH + h)*DD + t] = acc;
    }
}

// ---------------- fused attention per (b,q): AC+BD -> mask -> softmax -> PV -----------
__global__ void attn_kernel(const float* __restrict__ qbuf, const float* __restrict__ kbuf,
                            const float* __restrict__ vbuf, const float* __restrict__ qr,
                            const float* __restrict__ T,
                            const int* __restrict__ pos_s, const int* __restrict__ pos_e,
                            const int* __restrict__ seq_len, const int* __restrict__ lex_num,
                            const float* __restrict__ u, float* __restrict__ obuf)
{
    __shared__ float relb[32][260];
    __shared__ float qrl[NH][260];
    __shared__ float qu[256];
    __shared__ float sc[NH][260];
    const int t = threadIdx.x;
    const int row = blockIdx.x;                            // b*LT + q
    const int b = row >> 8;
    qu[t] = qbuf[row*DD + t] + u[t];
    #pragma unroll
    for (int h = 0; h < NH; ++h) qrl[h][t] = qr[(row*NH + h)*DD + t];
    const int totlen = seq_len[b] + lex_num[b];
    const int ps_q = pos_s[row], pe_q = pos_e[row];
    const int* psb = pos_s + b*LT;
    const int* peb = pos_e + b*LT;
    const int h = t >> 5, kk = t & 31;

    for (int K0 = 0; K0 < LT; K0 += 32) {
        __syncthreads();                                   // protect relb reuse
        for (int r = 0; r < 32; ++r) {                     // build 32 rel rows (coalesced)
            int kg = K0 + r;
            int sk = psb[kg], ek = peb[kg];
            int iss = ps_q - sk + 512, ise = ps_q - ek + 512;
            int ies = pe_q - sk + 512, iee = pe_q - ek + 512;
            float v = T[iss*DD + t] + T[(1025 + ise)*DD + t]
                    + T[(2*1025 + ies)*DD + t] + T[(3*1025 + iee)*DD + t];
            relb[r][t] = fmaxf(v, 0.f);
        }
        __syncthreads();
        // BD: dot(rel_row, qr[h]) over 256
        float s = 0.f;
        const float4* rp = (const float4*)&relb[kk][0];
        const float4* qp = (const float4*)&qrl[h][0];
        #pragma unroll 8
        for (int e4 = 0; e4 < 64; ++e4) {
            float4 r4 = rp[e4], q4 = qp[e4];
            s += r4.x*q4.x + r4.y*q4.y + r4.z*q4.z + r4.w*q4.w;
        }
        // AC: dot(qu[h], k_row[h]) over 32
        const float4* kp4 = (const float4*)&kbuf[(b*LT + K0 + kk)*DD + h*32];
        const float4* qup = (const float4*)&qu[h*32];
        #pragma unroll
        for (int d4 = 0; d4 < 8; ++d4) {
            float4 kv = kp4[d4], qv = qup[d4];
            s += kv.x*qv.x + kv.y*qv.y + kv.z*qv.z + kv.w*qv.w;
        }
        s *= 0.17677669529663687f;                         // 1/sqrt(32)
        if (K0 + kk >= totlen) s = NEGINF;
        sc[h][K0 + kk] = s;
    }
    __syncthreads();
    // softmax: 8 groups of 32 lanes, one row each
    {
        const int g = t >> 5, lane = t & 31;
        float vals[8];
        float m = -INFINITY;
        #pragma unroll
        for (int i = 0; i < 8; ++i) { vals[i] = sc[g][lane + 32*i]; m = fmaxf(m, vals[i]); }
        #pragma unroll
        for (int off = 16; off >= 1; off >>= 1) m = fmaxf(m, __shfl_xor(m, off, 32));
        float sum = 0.f;
        #pragma unroll
        for (int i = 0; i < 8; ++i) { vals[i] = expf(vals[i] - m); sum += vals[i]; }
        #pragma unroll
        for (int off = 16; off >= 1; off >>= 1) sum += __shfl_xor(sum, off, 32);
        float inv = 1.0f / sum;
        #pragma unroll
        for (int i = 0; i < 8; ++i) sc[g][lane + 32*i] = vals[i] * inv;
    }
    __syncthreads();
    // PV: out[j] = sum_k p[h(j)][k] * V[k][j]
    float acc = 0.f;
    const int hh = t >> 5;
    #pragma unroll 4
    for (int k = 0; k < LT; ++k)
        acc += sc[hh][k] * vbuf[(b*LT + k)*DD + t];
    obuf[row*DD + t] = acc;
}

// ---------------- LayerNorm over last dim (256) ---------------------------------------
__global__ void ln_kernel(const float* __restrict__ in, const float* __restrict__ g,
                          const float* __restrict__ bb, float* __restrict__ out)
{
    __shared__ float red[4];
    const int t = threadIdx.x, row = blockIdx.x;
    float v = in[row*DD + t];
    float s = v;
    #pragma unroll
    for (int off = 32; off >= 1; off >>= 1) s += __shfl_xor(s, off, 64);
    if ((t & 63) == 0) red[t >> 6] = s;
    __syncthreads();
    float m = (red[0] + red[1] + red[2] + red[3]) * (1.0f/256.0f);
    __syncthreads();
    float d = v - m;
    float s2 = d*d;
    #pragma unroll
    for (int off = 32; off >= 1; off >>= 1) s2 += __shfl_xor(s2, off, 64);
    if ((t & 63) == 0) red[t >> 6] = s2;
    __syncthreads();
    float var = (red[0] + red[1] + red[2] + red[3]) * (1.0f/256.0f);
    out[row*DD + t] = d * rsqrtf(var + 1e-5f) * g[t] + bb[t];
}

// ---------------- final: logits[b,s] = x[b,s] @ Wout + bout ---------------------------
__global__ void out_kernel(const float* __restrict__ x, const float* __restrict__ Wout,
                           const float* __restrict__ bout, float* __restrict__ out)
{
    __shared__ float xs[256];
    const int t = threadIdx.x, row = blockIdx.x;           // b*SS + s
    const int b = row / SS, s = row % SS;
    const float* xr = x + (b*LT + s)*DD;
    for (int i = t; i < DD; i += 64) xs[i] = xr[i];
    __syncthreads();
    if (t < 20) {
        float acc = bout[t];
        for (int d = 0; d < DD; ++d) acc += xs[d] * Wout[d*20 + t];
        out[row*20 + t] = acc;
    }
}

extern "C" void kernel_launch(void* const* d_in, const int* in_sizes, int n_in,
                              void* d_out, int out_size, void* d_ws, size_t ws_size,
                              hipStream_t stream)
{
    const int*   lattice = (const int*)d_in[0];
    const int*   bigrams = (const int*)d_in[1];
    const int*   seq_len = (const int*)d_in[2];
    const int*   lex_num = (const int*)d_in[3];
    const int*   pos_s   = (const int*)d_in[4];
    const int*   pos_e   = (const int*)d_in[5];
    /* d_in[6] target: unused (CRF loss omitted in reference) */
    const float* bert    = (const float*)d_in[7];
    const float* lat_t   = (const float*)d_in[8];
    const float* big_t   = (const float*)d_in[9];
    const float* Wc      = (const float*)d_in[10];
    const float* bc      = (const float*)d_in[11];
    const float* Wl      = (const float*)d_in[12];
    const float* bl      = (const float*)d_in[13];
    const float* W_fus   = (const float*)d_in[14];
    const float* b_fus   = (const float*)d_in[15];
    const float* Wq      = (const float*)d_in[16];
    const float* bq      = (const float*)d_in[17];
    const float* Wk      = (const float*)d_in[18];
    const float* bk      = (const float*)d_in[19];
    const float* Wv      = (const float*)d_in[20];
    const float* bv      = (const float*)d_in[21];
    const float* Wr      = (const float*)d_in[22];
    /* d_in[23] br: dropped — constant over k, softmax shift-invariant */
    const float* u_bias  = (const float*)d_in[24];
    const float* v_bias  = (const float*)d_in[25];
    const float* Wo      = (const float*)d_in[26];
    const float* bo      = (const float*)d_in[27];
    const float* ln1g    = (const float*)d_in[28];
    const float* ln1b    = (const float*)d_in[29];
    const float* W1      = (const float*)d_in[30];
    const float* b1      = (const float*)d_in[31];
    const float* W2      = (const float*)d_in[32];
    const float* b2      = (const float*)d_in[33];
    const float* ln2g    = (const float*)d_in[34];
    const float* ln2b    = (const float*)d_in[35];
    const float* Wout    = (const float*)d_in[36];
    const float* bout    = (const float*)d_in[37];

    float* ws = (float*)d_ws;
    float* x    = ws;  ws += NB*LT*DD;
    float* T    = ws;  ws += 4*1025*DD;
    float* WrT  = ws;  ws += NLAYER*DD*DD;
    float* qb   = ws;  ws += NB*LT*DD;
    float* kb   = ws;  ws += NB*LT*DD;
    float* vbf  = ws;  ws += NB*LT*DD;
    float* ob   = ws;  ws += NB*LT*DD;
    float* qr   = ws;  ws += NB*LT*NH*DD;
    float* t1   = ws;  ws += NB*LT*DD;
    float* x2   = ws;  ws += NB*LT*DD;
    float* hb   = ws;  ws += NB*LT*FFD;
    float* t2   = ws;  ws += NB*LT*DD;

    const int M = NB*LT;

    embed_kernel<<<M/8, 256, 0, stream>>>(lattice, bigrams, seq_len, lex_num,
                                          bert, lat_t, big_t, Wc, bc, Wl, bl, x);
    build_T<<<dim3(257, 4), 256, 0, stream>>>(W_fus, b_fus, T);
    transpose_wr<<<NLAYER*DD, 256, 0, stream>>>(Wr, WrT);

    for (int l = 0; l < NLAYER; ++l) {
        gemm32<false><<<dim3(DD/32, M/32), 256, 0, stream>>>(x, Wq + l*DD*DD, bq + l*DD, nullptr, qb, M, DD, DD);
        gemm32<false><<<dim3(DD/32, M/32), 256, 0, stream>>>(x, Wk + l*DD*DD, bk + l*DD, nullptr, kb, M, DD, DD);
        gemm32<false><<<dim3(DD/32, M/32), 256, 0, stream>>>(x, Wv + l*DD*DD, bv + l*DD, nullptr, vbf, M, DD, DD);
        qr_kernel<<<M, 256, 0, stream>>>(qb, v_bias + l*DD, WrT + l*DD*DD, qr);
        attn_kernel<<<M, 256, 0, stream>>>(qb, kb, vbf, qr, T, pos_s, pos_e,
                                           seq_len, lex_num, u_bias + l*DD, ob);
        gemm32<false><<<dim3(DD/32, M/32), 256, 0, stream>>>(ob, Wo + l*DD*DD, bo + l*DD, x, t1, M, DD, DD);
        ln_kernel<<<M, 256, 0, stream>>>(t1, ln1g + l*DD, ln1b + l*DD, x2);
        gemm32<true><<<dim3(FFD/32, M/32), 256, 0, stream>>>(x2, W1 + l*DD*FFD, b1 + l*FFD, nullptr, hb, M, FFD, DD);
        gemm32<false><<<dim3(DD/32, M/32), 256, 0, stream>>>(hb, W2 + l*FFD*DD, b2 + l*DD, x2, t2, M, DD, FFD);
        ln_kernel<<<M, 256, 0, stream>>>(t2, ln2g + l*DD, ln2b + l*DD, x);
    }
    out_kernel<<<NB*SS, 64, 0, stream>>>(x, Wout, bout, (float*)d_out);
}

// Round 2
// 554.600 us; speedup vs baseline: 1.3745x; 1.3745x over previous
//
#include <hip/hip_runtime.h>
#include <math.h>

#define NB 4
#define SS 200
#define LT 256
#define DD 256
#define NH 8
#define NLAYER 2
#define FFD 1024
#define BERTD 768
#define CIN 868
#define KG 992                 // padded embed GEMM K (868 + 50 + 2 bias cols + pad)
#define NEGINF -1e15f

// ---------------- gather combined embed input G[1024][992] ----------------------------
// cols 0..867: raw_char*maskC ; 868..917: raw*maskL ; 918: maskC ; 919: maskL ; rest 0
__global__ void gather_kernel(const int* __restrict__ lattice, const int* __restrict__ bigrams,
                              const int* __restrict__ seq_len, const int* __restrict__ lex_num,
                              const float* __restrict__ bert, const float* __restrict__ lat_t,
                              const float* __restrict__ big_t, float* __restrict__ G)
{
    const int row = blockIdx.x, t = threadIdx.x;
    const int b = row >> 8, l = row & 255;
    const int sl = seq_len[b], tl = sl + lex_num[b];
    const float mC = (l < sl) ? 1.f : 0.f;
    const float mL = (l >= sl && l < tl) ? 1.f : 0.f;
    const int lat = lattice[row];
    const int big = (l < SS) ? bigrams[b*SS + l] : 0;
    for (int i = t; i < KG; i += 256) {
        float v;
        if (i < 50)        v = lat_t[lat*50 + i] * mC;
        else if (i < 100)  v = (l < SS) ? big_t[big*50 + (i-50)] * mC : 0.f;
        else if (i < 868)  v = (l < SS) ? bert[(b*SS + l)*BERTD + (i-100)] * mC : 0.f;
        else if (i < 918)  v = lat_t[lat*50 + (i-868)] * mL;
        else if (i == 918) v = mC;
        else if (i == 919) v = mL;
        else               v = 0.f;
        G[row*KG + i] = v;
    }
}

// ---------------- Wcomb[992][256] = [Wc ; Wl ; bc ; bl ; 0] ---------------------------
__global__ void wcomb_kernel(const float* __restrict__ Wc, const float* __restrict__ bc,
                             const float* __restrict__ Wl, const float* __restrict__ bl,
                             float* __restrict__ Wcomb)
{
    const int r = blockIdx.x, t = threadIdx.x;
    float v;
    if (r < 868)      v = Wc[r*DD + t];
    else if (r < 918) v = Wl[(r-868)*DD + t];
    else if (r == 918) v = bc[t];
    else if (r == 919) v = bl[t];
    else               v = 0.f;
    Wcomb[r*DD + t] = v;
}

// ---------------- T[k][p][o] = pe[p] @ W_fus[k]  (b_fus folded into k==0) -------------
__global__ void build_T(const float* __restrict__ W_fus, const float* __restrict__ b_fus,
                        float* __restrict__ T)
{
    __shared__ float pe[4][256];
    const int t = threadIdx.x, k = blockIdx.y;
    const int p0 = blockIdx.x * 4;
    const float fr = expf(-(float)(t & 127) * (9.210340371976184f / 127.0f));
    #pragma unroll
    for (int i = 0; i < 4; ++i) {
        int p = p0 + i;
        float arg = (float)(p > 1024 ? 0 : p) * fr;
        pe[i][t] = (t < 128) ? sinf(arg) : cosf(arg);
    }
    __syncthreads();
    float acc[4];
    const float bias = (k == 0) ? b_fus[t] : 0.f;
    #pragma unroll
    for (int i = 0; i < 4; ++i) acc[i] = bias;
    const float* W = W_fus + k * DD * DD;
    for (int e = 0; e < DD; ++e) {
        float w = W[e*DD + t];
        #pragma unroll
        for (int i = 0; i < 4; ++i) acc[i] += pe[i][e] * w;
    }
    #pragma unroll
    for (int i = 0; i < 4; ++i) {
        int p = p0 + i;
        if (p <= 1024) T[(k*1025 + p)*DD + t] = acc[i];
    }
}

// ---------------- Rcc[p] = relu(T0[p]+T1[p]+T2[p]+T3[p])  (char-char collapse) --------
__global__ void rcc_kernel(const float* __restrict__ T, float* __restrict__ Rcc)
{
    const int p = blockIdx.x, t = threadIdx.x;
    float v = T[p*DD + t] + T[(1025 + p)*DD + t] + T[(2050 + p)*DD + t] + T[(3075 + p)*DD + t];
    Rcc[p*DD + t] = fmaxf(v, 0.f);
}

// ---------------- WrT[l][j][e] = Wr[l][e][j] ------------------------------------------
__global__ void transpose_wr(const float* __restrict__ Wr, float* __restrict__ WrT)
{
    const int j = blockIdx.x & 255, l = blockIdx.x >> 8, e = threadIdx.x;
    WrT[(l*DD + j)*DD + e] = Wr[l*DD*DD + e*DD + j];
}

// ---------------- pack Wq|Wk|Wv -> Wqkv[l][256][768], biases -> bqkv ------------------
__global__ void pack_qkv(const float* __restrict__ Wq, const float* __restrict__ Wk,
                         const float* __restrict__ Wv, const float* __restrict__ bq,
                         const float* __restrict__ bk, const float* __restrict__ bv,
                         float* __restrict__ Wqkv, float* __restrict__ bqkv)
{
    const int l = blockIdx.x >> 8, d = blockIdx.x & 255, t = threadIdx.x;
    Wqkv[(l*DD + d)*768 + t]       = Wq[(l*DD + d)*DD + t];
    Wqkv[(l*DD + d)*768 + 256 + t] = Wk[(l*DD + d)*DD + t];
    Wqkv[(l*DD + d)*768 + 512 + t] = Wv[(l*DD + d)*DD + t];
    if (d == 0) {
        bqkv[l*768 + t]       = bq[l*DD + t];
        bqkv[l*768 + 256 + t] = bk[l*DD + t];
        bqkv[l*768 + 512 + t] = bv[l*DD + t];
    }
}

// ---------------- tiled f32 GEMM: C = (A@W + bias [+ resid]) [relu] -------------------
template<int BM, int BN, bool RELU>
__global__ __launch_bounds__(256) void gemmv2(const float* __restrict__ A, const float* __restrict__ W,
                       const float* __restrict__ bias, const float* __restrict__ resid,
                       float* __restrict__ C, int M, int N, int K)
{
    static_assert(BM*8 % 256 == 0 && 8*BN % 256 == 0, "loader mapping");
    __shared__ float As[32][BM+2];
    __shared__ float Bs[32][BN+4];
    constexpr int TM = BM/16, TN = BN/16;
    const int t = threadIdx.x;
    const int row0 = blockIdx.y*BM, col0 = blockIdx.x*BN;
    const int tr = (t>>4)*TM, tc = (t&15)*TN;
    float acc[TM][TN] = {};
    for (int k0 = 0; k0 < K; k0 += 32) {
        #pragma unroll
        for (int i = 0; i < BM/32; ++i) {              // A tile: BM rows x 32 k
            int slot = t + i*256;
            int r = slot >> 3, kq = (slot & 7)*4;
            float4 av = *(const float4*)&A[(row0+r)*K + k0 + kq];
            As[kq][r] = av.x; As[kq+1][r] = av.y; As[kq+2][r] = av.z; As[kq+3][r] = av.w;
        }
        #pragma unroll
        for (int i = 0; i < BN/32; ++i) {              // B tile: 32 k x BN cols
            int slot = t + i*256;
            int kk = slot / (BN/4), nq = (slot % (BN/4))*4;
            *(float4*)&Bs[kk][nq] = *(const float4*)&W[(k0+kk)*N + col0 + nq];
        }
        __syncthreads();
        #pragma unroll
        for (int kk = 0; kk < 32; ++kk) {
            float a[TM], bb[TN];
            #pragma unroll
            for (int i = 0; i < TM; ++i) a[i] = As[kk][tr+i];
            #pragma unroll
            for (int j = 0; j < TN; ++j) bb[j] = Bs[kk][tc+j];
            #pragma unroll
            for (int i = 0; i < TM; ++i)
                #pragma unroll
                for (int j = 0; j < TN; ++j) acc[i][j] += a[i]*bb[j];
        }
        __syncthreads();
    }
    #pragma unroll
    for (int i = 0; i < TM; ++i) {
        const int r = row0 + tr + i, c0 = col0 + tc;
        #pragma unroll
        for (int j = 0; j < TN; ++j) {
            float v = acc[i][j] + (bias ? bias[c0+j] : 0.f);
            if (resid) v += resid[r*N + c0 + j];
            if (RELU) v = fmaxf(v, 0.f);
            acc[i][j] = v;
        }
        if constexpr (TN == 4) {
            float4 v = make_float4(acc[i][0], acc[i][1], acc[i][2], acc[i][3]);
            *(float4*)&C[r*N + c0] = v;
        } else {
            float2 v = make_float2(acc[i][0], acc[i][1]);
            *(float2*)&C[r*N + c0] = v;
        }
    }
}

// ---------------- qr[row,h,e] = sum_d (Q[row,h*32+d]+vb[h*32+d]) * WrT[h*32+d][e] -----
__global__ __launch_bounds__(256) void qr_v2(const float* __restrict__ qkvb, const float* __restrict__ vb,
                      const float* __restrict__ WrT, float* __restrict__ qr)
{
    __shared__ float qv[4][256];
    const int t = threadIdx.x, row0 = blockIdx.x * 4;
    #pragma unroll
    for (int r = 0; r < 4; ++r) qv[r][t] = qkvb[(row0+r)*768 + t] + vb[t];
    __syncthreads();
    #pragma unroll
    for (int h = 0; h < NH; ++h) {
        float acc[4] = {0.f, 0.f, 0.f, 0.f};
        const float* wt = WrT + (h*32)*DD;
        for (int d = 0; d < 32; ++d) {
            float w = wt[d*DD + t];
            #pragma unroll
            for (int r = 0; r < 4; ++r) acc[r] += qv[r][h*32 + d] * w;
        }
        #pragma unroll
        for (int r = 0; r < 4; ++r) qr[((row0+r)*NH + h)*DD + t] = acc[r];
    }
}

// ---------------- fused attention per (b,q) -------------------------------------------
__global__ __launch_bounds__(256) void attn_v2(
    const float* __restrict__ qkvb, const float* __restrict__ qr,
    const float* __restrict__ T, const float* __restrict__ Rcc,
    const int* __restrict__ pos_s, const int* __restrict__ pos_e,
    const int* __restrict__ seq_len, const int* __restrict__ lex_num,
    const float* __restrict__ u, float* __restrict__ obuf)
{
    __shared__ float relb[32][260];
    __shared__ float qrl[NH][260];
    __shared__ float qu[256];
    __shared__ float sc[NH][260];
    __shared__ float redbuf[2048];
    const int t = threadIdx.x;
    const int row = blockIdx.x;
    const int b = row >> 8, q = row & 255;
    const int totlen = seq_len[b] + lex_num[b];
    if (q >= SS && q >= totlen) {                     // row never consumed downstream
        obuf[row*DD + t] = 0.f;
        return;
    }
    qu[t] = qkvb[row*768 + t] + u[t];
    #pragma unroll
    for (int h = 0; h < NH; ++h) qrl[h][t] = qr[(row*NH + h)*DD + t];
    const int ps_q = pos_s[row], pe_q = pos_e[row];
    const int* psb = pos_s + b*LT;
    const int* peb = pos_e + b*LT;
    const bool qchar = (q < SS);
    const int br = t >> 3, bc4 = (t & 7)*4;           // build mapping
    const int dk = t & 31, seg = t >> 5;              // dot mapping

    for (int K0 = 0; K0 < totlen; K0 += 32) {
        __syncthreads();
        {   // build 32 rel rows
            const int kg = K0 + br;
            const int sk = psb[kg], ek = peb[kg];
            if (qchar && kg < SS) {
                const float* rp = Rcc + (ps_q - sk + 512)*DD;
                #pragma unroll
                for (int i = 0; i < 8; ++i) {
                    int e = i*32 + bc4;
                    *(float4*)&relb[br][e] = *(const float4*)&rp[e];
                }
            } else {
                const float* t0 = T + (ps_q - sk + 512)*DD;
                const float* t1 = T + (1025 + ps_q - ek + 512)*DD;
                const float* t2 = T + (2050 + pe_q - sk + 512)*DD;
                const float* t3 = T + (3075 + pe_q - ek + 512)*DD;
                #pragma unroll
                for (int i = 0; i < 8; ++i) {
                    int e = i*32 + bc4;
                    float4 a = *(const float4*)&t0[e];
                    float4 bb = *(const float4*)&t1[e];
                    float4 c = *(const float4*)&t2[e];
                    float4 d = *(const float4*)&t3[e];
                    float4 v;
                    v.x = fmaxf(a.x + bb.x + c.x + d.x, 0.f);
                    v.y = fmaxf(a.y + bb.y + c.y + d.y, 0.f);
                    v.z = fmaxf(a.z + bb.z + c.z + d.z, 0.f);
                    v.w = fmaxf(a.w + bb.w + c.w + d.w, 0.f);
                    *(float4*)&relb[br][e] = v;
                }
            }
        }
        __syncthreads();
        {   // BD partial dots: thread (k=dk, e-segment seg) for all 8 heads; AC for head==seg
            float a[8] = {0.f,0.f,0.f,0.f,0.f,0.f,0.f,0.f};
            const int e0 = seg*32;
            #pragma unroll
            for (int e4 = 0; e4 < 8; ++e4) {
                float4 r4 = *(const float4*)&relb[dk][e0 + e4*4];
                #pragma unroll
                for (int h = 0; h < 8; ++h) {
                    float4 q4 = *(const float4*)&qrl[h][e0 + e4*4];
                    a[h] += r4.x*q4.x + r4.y*q4.y + r4.z*q4.z + r4.w*q4.w;
                }
            }
            {
                const float* kp = qkvb + (size_t)(b*LT + K0 + dk)*768 + 256 + seg*32;
                float acv = 0.f;
                #pragma unroll
                for (int d4 = 0; d4 < 8; ++d4) {
                    float4 kv = *(const float4*)&kp[d4*4];
                    float4 qv = *(const float4*)&qu[seg*32 + d4*4];
                    acv += kv.x*qv.x + kv.y*qv.y + kv.z*qv.z + kv.w*qv.w;
                }
                a[seg] += acv;
            }
            float4* rb = (float4*)&redbuf[(seg*32 + dk)*8];
            rb[0] = make_float4(a[0], a[1], a[2], a[3]);
            rb[1] = make_float4(a[4], a[5], a[6], a[7]);
        }
        __syncthreads();
        {   // reduce 8 segments -> score
            const int k = t >> 3, h = t & 7;
            float s = 0.f;
            #pragma unroll
            for (int g = 0; g < 8; ++g) s += redbuf[g*256 + t];
            s *= 0.17677669529663687f;                // 1/sqrt(32)
            const int kg = K0 + k;
            if (kg >= totlen) s = NEGINF;
            sc[h][kg] = s;
        }
    }
    __syncthreads();
    {   // softmax: 8 lane-groups of 32, one head each
        const int g = t >> 5, lane = t & 31;
        float vals[8];
        float m = -INFINITY;
        #pragma unroll
        for (int i = 0; i < 8; ++i) {
            int kidx = lane + 32*i;
            vals[i] = (kidx < totlen) ? sc[g][kidx] : NEGINF;
            m = fmaxf(m, vals[i]);
        }
        #pragma unroll
        for (int off = 16; off >= 1; off >>= 1) m = fmaxf(m, __shfl_xor(m, off, 32));
        float sum = 0.f;
        #pragma unroll
        for (int i = 0; i < 8; ++i) { vals[i] = expf(vals[i] - m); sum += vals[i]; }
        #pragma unroll
        for (int off = 16; off >= 1; off >>= 1) sum += __shfl_xor(sum, off, 32);
        const float inv = 1.0f / sum;
        #pragma unroll
        for (int i = 0; i < 8; ++i) sc[g][lane + 32*i] = vals[i] * inv;
    }
    __syncthreads();
    {   // PV: thread (j4 = 4 cols, kr = k-phase), partial over k ≡ kr (mod 4)
        const int j4 = (t & 63)*4, kr = t >> 6;
        const int h = j4 >> 5;
        float4 acc = make_float4(0.f, 0.f, 0.f, 0.f);
        const float* vp = qkvb + (size_t)(b*LT)*768 + 512 + j4;
        for (int k = kr; k < totlen; k += 4) {
            const float p = sc[h][k];
            float4 v = *(const float4*)&vp[(size_t)k*768];
            acc.x += p*v.x; acc.y += p*v.y; acc.z += p*v.z; acc.w += p*v.w;
        }
        *(float4*)&redbuf[kr*256 + j4] = acc;
    }
    __syncthreads();
    obuf[row*DD + t] = redbuf[t] + redbuf[256 + t] + redbuf[512 + t] + redbuf[768 + t];
}

// ---------------- LayerNorm over last dim (256) ---------------------------------------
__global__ void ln_kernel(const float* __restrict__ in, const float* __restrict__ g,
                          const float* __restrict__ bb, float* __restrict__ out)
{
    __shared__ float red[4];
    const int t = threadIdx.x, row = blockIdx.x;
    float v = in[row*DD + t];
    float s = v;
    #pragma unroll
    for (int off = 32; off >= 1; off >>= 1) s += __shfl_xor(s, off, 64);
    if ((t & 63) == 0) red[t >> 6] = s;
    __syncthreads();
    float m = (red[0] + red[1] + red[2] + red[3]) * (1.0f/256.0f);
    __syncthreads();
    float d = v - m;
    float s2 = d*d;
    #pragma unroll
    for (int off = 32; off >= 1; off >>= 1) s2 += __shfl_xor(s2, off, 64);
    if ((t & 63) == 0) red[t >> 6] = s2;
    __syncthreads();
    float var = (red[0] + red[1] + red[2] + red[3]) * (1.0f/256.0f);
    out[row*DD + t] = d * rsqrtf(var + 1e-5f) * g[t] + bb[t];
}

// ---------------- final: logits[b,s] = x[b,s] @ Wout + bout ---------------------------
__global__ void out_kernel(const float* __restrict__ x, const float* __restrict__ Wout,
                           const float* __restrict__ bout, float* __restrict__ out)
{
    __shared__ float xs[256];
    const int t = threadIdx.x, row = blockIdx.x;
    const int b = row / SS, s = row % SS;
    const float* xr = x + (b*LT + s)*DD;
    for (int i = t; i < DD; i += 64) xs[i] = xr[i];
    __syncthreads();
    if (t < 20) {
        float acc = bout[t];
        for (int d = 0; d < DD; ++d) acc += xs[d] * Wout[d*20 + t];
        out[row*20 + t] = acc;
    }
}

extern "C" void kernel_launch(void* const* d_in, const int* in_sizes, int n_in,
                              void* d_out, int out_size, void* d_ws, size_t ws_size,
                              hipStream_t stream)
{
    const int*   lattice = (const int*)d_in[0];
    const int*   bigrams = (const int*)d_in[1];
    const int*   seq_len = (const int*)d_in[2];
    const int*   lex_num = (const int*)d_in[3];
    const int*   pos_s   = (const int*)d_in[4];
    const int*   pos_e   = (const int*)d_in[5];
    /* d_in[6] target: unused */
    const float* bert    = (const float*)d_in[7];
    const float* lat_t   = (const float*)d_in[8];
    const float* big_t   = (const float*)d_in[9];
    const float* Wc      = (const float*)d_in[10];
    const float* bc      = (const float*)d_in[11];
    const float* Wl      = (const float*)d_in[12];
    const float* bl      = (const float*)d_in[13];
    const float* W_fus   = (const float*)d_in[14];
    const float* b_fus   = (const float*)d_in[15];
    const float* Wq      = (const float*)d_in[16];
    const float* bq      = (const float*)d_in[17];
    const float* Wk      = (const float*)d_in[18];
    const float* bk      = (const float*)d_in[19];
    const float* Wv      = (const float*)d_in[20];
    const float* bv      = (const float*)d_in[21];
    const float* Wr      = (const float*)d_in[22];
    /* d_in[23] br: dropped — constant over k, softmax shift-invariant */
    const float* u_bias  = (const float*)d_in[24];
    const float* v_bias  = (const float*)d_in[25];
    const float* Wo      = (const float*)d_in[26];
    const float* bo      = (const float*)d_in[27];
    const float* ln1g    = (const float*)d_in[28];
    const float* ln1b    = (const float*)d_in[29];
    const float* W1      = (const float*)d_in[30];
    const float* b1      = (const float*)d_in[31];
    const float* W2      = (const float*)d_in[32];
    const float* b2      = (const float*)d_in[33];
    const float* ln2g    = (const float*)d_in[34];
    const float* ln2b    = (const float*)d_in[35];
    const float* Wout    = (const float*)d_in[36];
    const float* bout    = (const float*)d_in[37];

    float* ws = (float*)d_ws;
    float* qkvb = ws;  ws += NB*LT*768;        // [1024][768]
    float* ob   = ws;  ws += NB*LT*DD;
    float* t1   = ws;  ws += NB*LT*DD;
    float* x2   = ws;  ws += NB*LT*DD;
    float* t2   = ws;  ws += NB*LT*DD;
    float* hb   = ws;  ws += NB*LT*FFD;
    float* x    = ws;  ws += NB*LT*DD;
    float* T    = ws;  ws += 4*1025*DD;
    float* Rcc  = ws;  ws += 1025*DD;
    float* WrT  = ws;  ws += NLAYER*DD*DD;
    float* Wqkv = ws;  ws += NLAYER*DD*768;
    float* bqkv = ws;  ws += NLAYER*768;
    float* qr   = ws;  ws += NB*LT*NH*DD;
    float* G     = qkvb;   // alias: G[1024][992] (needs qkvb+ob span), dead before QKV gemm
    float* Wcomb = t1;     // alias: Wcomb[992][256], dead before first t1 write

    const int M = NB*LT;

    gather_kernel<<<M, 256, 0, stream>>>(lattice, bigrams, seq_len, lex_num,
                                         bert, lat_t, big_t, G);
    wcomb_kernel<<<KG, 256, 0, stream>>>(Wc, bc, Wl, bl, Wcomb);
    build_T<<<dim3(257, 4), 256, 0, stream>>>(W_fus, b_fus, T);
    transpose_wr<<<NLAYER*DD, 256, 0, stream>>>(Wr, WrT);
    pack_qkv<<<NLAYER*DD, 256, 0, stream>>>(Wq, Wk, Wv, bq, bk, bv, Wqkv, bqkv);
    rcc_kernel<<<1025, 256, 0, stream>>>(T, Rcc);

    // embed GEMM: x = G @ Wcomb   (masks + biases folded into G/Wcomb)
    gemmv2<32,32,false><<<dim3(DD/32, M/32), 256, 0, stream>>>(G, Wcomb, nullptr, nullptr, x, M, DD, KG);

    for (int l = 0; l < NLAYER; ++l) {
        gemmv2<32,64,false><<<dim3(768/64, M/32), 256, 0, stream>>>(
            x, Wqkv + l*DD*768, bqkv + l*768, nullptr, qkvb, M, 768, DD);
        qr_v2<<<M/4, 256, 0, stream>>>(qkvb, v_bias + l*DD, WrT + l*DD*DD, qr);
        attn_v2<<<M, 256, 0, stream>>>(qkvb, qr, T, Rcc, pos_s, pos_e,
                                       seq_len, lex_num, u_bias + l*DD, ob);
        gemmv2<32,32,false><<<dim3(DD/32, M/32), 256, 0, stream>>>(
            ob, Wo + l*DD*DD, bo + l*DD, x, t1, M, DD, DD);
        ln_kernel<<<M, 256, 0, stream>>>(t1, ln1g + l*DD, ln1b + l*DD, x2);
        gemmv2<64,64,true><<<dim3(FFD/64, M/64), 256, 0, stream>>>(
            x2, W1 + l*DD*FFD, b1 + l*FFD, nullptr, hb, M, FFD, DD);
        gemmv2<32,32,false><<<dim3(DD/32, M/32), 256, 0, stream>>>(
            hb, W2 + l*FFD*DD, b2 + l*DD, x2, t2, M, DD, FFD);
        ln_kernel<<<M, 256, 0, stream>>>(t2, ln2g + l*DD, ln2b + l*DD, x);
    }
    out_kernel<<<NB*SS, 64, 0, stream>>>(x, Wout, bout, (float*)d_out);
}

// Round 3
// 512.198 us; speedup vs baseline: 1.4883x; 1.0828x over previous
//
#include <hip/hip_runtime.h>
#include <math.h>

#define NB 4
#define SS 200
#define LT 256
#define DD 256
#define NH 8
#define NLAYER 2
#define FFD 1024
#define BERTD 768
#define CIN 868
#define KG 992
#define NEGINF -1e15f

typedef __attribute__((ext_vector_type(8))) short bf16x8;
typedef __attribute__((ext_vector_type(4))) float f32x4;
typedef __attribute__((ext_vector_type(8))) unsigned short u16x8;
typedef __attribute__((ext_vector_type(4))) unsigned short u16x4;

__device__ inline float bf2f(unsigned short h) {
    union { unsigned int u; float f; } v; v.u = ((unsigned int)h) << 16; return v.f;
}
__device__ inline unsigned short f2bf(float x) {
    union { float f; unsigned int u; } v; v.f = x;
    unsigned int r = v.u + 0x7fffu + ((v.u >> 16) & 1u);
    return (unsigned short)(r >> 16);
}

// ---------------- gather combined embed input G[1024][992] ----------------------------
__global__ void gather_kernel(const int* __restrict__ lattice, const int* __restrict__ bigrams,
                              const int* __restrict__ seq_len, const int* __restrict__ lex_num,
                              const float* __restrict__ bert, const float* __restrict__ lat_t,
                              const float* __restrict__ big_t, float* __restrict__ G)
{
    const int row = blockIdx.x, t = threadIdx.x;
    const int b = row >> 8, l = row & 255;
    const int sl = seq_len[b], tl = sl + lex_num[b];
    const float mC = (l < sl) ? 1.f : 0.f;
    const float mL = (l >= sl && l < tl) ? 1.f : 0.f;
    const int lat = lattice[row];
    const int big = (l < SS) ? bigrams[b*SS + l] : 0;
    for (int i = t; i < KG; i += 256) {
        float v;
        if (i < 50)        v = lat_t[lat*50 + i] * mC;
        else if (i < 100)  v = (l < SS) ? big_t[big*50 + (i-50)] * mC : 0.f;
        else if (i < 868)  v = (l < SS) ? bert[(b*SS + l)*BERTD + (i-100)] * mC : 0.f;
        else if (i < 918)  v = lat_t[lat*50 + (i-868)] * mL;
        else if (i == 918) v = mC;
        else if (i == 919) v = mL;
        else               v = 0.f;
        G[row*KG + i] = v;
    }
}

// ---------------- Wcomb[992][256] = [Wc ; Wl ; bc ; bl ; 0] ---------------------------
__global__ void wcomb_kernel(const float* __restrict__ Wc, const float* __restrict__ bc,
                             const float* __restrict__ Wl, const float* __restrict__ bl,
                             float* __restrict__ Wcomb)
{
    const int r = blockIdx.x, t = threadIdx.x;
    float v;
    if (r < 868)      v = Wc[r*DD + t];
    else if (r < 918) v = Wl[(r-868)*DD + t];
    else if (r == 918) v = bc[t];
    else if (r == 919) v = bl[t];
    else               v = 0.f;
    Wcomb[r*DD + t] = v;
}

// ---------------- PE[1088][256] f32 (rows >1024 zero) ---------------------------------
__global__ void pe_kernel(float* __restrict__ PEf)
{
    const int p = blockIdx.x, t = threadIdx.x;
    float v = 0.f;
    if (p <= 1024) {
        const float fr = expf(-(float)(t & 127) * (9.210340371976184f / 127.0f));
        const float arg = (float)p * fr;
        v = (t < 128) ? sinf(arg) : cosf(arg);
    }
    PEf[p*DD + t] = v;
}

// ---------------- small packs: bqkv[2][768], bfus4[1024] ------------------------------
__global__ void smallpack(const float* __restrict__ bq, const float* __restrict__ bk,
                          const float* __restrict__ bv, const float* __restrict__ b_fus,
                          float* __restrict__ bqkv, float* __restrict__ bfus4)
{
    const int t = threadIdx.x;
    for (int l = 0; l < NLAYER; ++l) {
        bqkv[l*768 + t]       = bq[l*DD + t];
        bqkv[l*768 + 256 + t] = bk[l*DD + t];
        bqkv[l*768 + 512 + t] = bv[l*DD + t];
    }
    bfus4[t] = b_fus[t];
    bfus4[256 + t] = 0.f; bfus4[512 + t] = 0.f; bfus4[768 + t] = 0.f;
}

// ---------------- WrT[l][j][e] = Wr[l][e][j] (f32, for qr) ----------------------------
__global__ void transpose_wr(const float* __restrict__ Wr, float* __restrict__ WrT)
{
    const int j = blockIdx.x & 255, l = blockIdx.x >> 8, e = threadIdx.x;
    WrT[(l*DD + j)*DD + e] = Wr[l*DD*DD + e*DD + j];
}

// ---------------- merged transpose+split of all GEMM weights --------------------------
// dst[n][k] = src[k][n], split into bf16 hi/lo
__global__ void trans_all(const float* __restrict__ Wcomb, const float* __restrict__ Wq,
                          const float* __restrict__ Wk, const float* __restrict__ Wv,
                          const float* __restrict__ Wo, const float* __restrict__ W1,
                          const float* __restrict__ W2, const float* __restrict__ Wfus,
                          unsigned short* WcombT_h, unsigned short* WcombT_l,
                          unsigned short* WqkvT_h,  unsigned short* WqkvT_l,
                          unsigned short* WoT_h,    unsigned short* WoT_l,
                          unsigned short* W1T_h,    unsigned short* W1T_l,
                          unsigned short* W2T_h,    unsigned short* W2T_l,
                          unsigned short* WfusT_h,  unsigned short* WfusT_l)
{
    const int z = blockIdx.z, y = blockIdx.y, tx = blockIdx.x, t = threadIdx.x;
    const float* src; unsigned short *dh, *dl; int K, N;
    switch (z) {
        case 0: if (y) return; K = KG;  N = 256;  src = Wcomb; dh = WcombT_h; dl = WcombT_l; break;
        case 1: { if (y >= 6) return; int l = y/3, s = y%3; K = 256; N = 256;
                  src = (s==0 ? Wq : s==1 ? Wk : Wv) + l*65536;
                  dh = WqkvT_h + (l*768 + s*256)*256; dl = WqkvT_l + (l*768 + s*256)*256; } break;
        case 2: if (y >= 2) return; K = 256; N = 256;  src = Wo + y*65536;  dh = WoT_h + y*65536;  dl = WoT_l + y*65536;  break;
        case 3: if (y >= 2) return; K = 256; N = 1024; src = W1 + y*262144; dh = W1T_h + y*262144; dl = W1T_l + y*262144; break;
        case 4: if (y >= 2) return; K = 1024; N = 256; src = W2 + y*262144; dh = W2T_h + y*262144; dl = W2T_l + y*262144; break;
        case 5: if (y >= 4) return; K = 256; N = 256;  src = Wfus + y*65536; dh = WfusT_h + y*65536; dl = WfusT_l + y*65536; break;
        default: return;
    }
    const int tiles_x = N >> 5;
    const int tn = tx % tiles_x, tk = tx / tiles_x;
    if (tk >= (K >> 5)) return;
    __shared__ float s[32][33];
    const int lr = t >> 5, lc = t & 31;
    #pragma unroll
    for (int i = 0; i < 4; ++i)
        s[lr + 8*i][lc] = src[(size_t)(tk*32 + lr + 8*i)*N + tn*32 + lc];
    __syncthreads();
    #pragma unroll
    for (int i = 0; i < 4; ++i) {
        const int n = tn*32 + lr + 8*i, k = tk*32 + lc;
        const float x = s[lc][lr + 8*i];
        const unsigned short hh = f2bf(x);
        dh[(size_t)n*K + k] = hh;
        dl[(size_t)n*K + k] = f2bf(x - bf2f(hh));
    }
}

// ---------------- MFMA GEMM: C = A @ B (+bias)(+resid)(relu), near-f32 via split-bf16 -
// A: f32 [M][K] (M%64==0, K%32==0), BT: bf16 hi/lo [N][K], C: f32 [M][N]
template<int BN, bool RELU>
__global__ __launch_bounds__(256) void gemm_bt_mfma(
    const float* __restrict__ A, const unsigned short* __restrict__ BTh,
    const unsigned short* __restrict__ BTl, const float* __restrict__ bias,
    const float* __restrict__ resid, float* __restrict__ C, int M, int N, int K)
{
    constexpr int NT = BN / 32;              // n-frags per wave (2 or 1)
    __shared__ unsigned short Ah[64*40], Al[64*40];
    __shared__ unsigned short Bh[BN*40], Bl[BN*40];
    const int t = threadIdx.x;
    const int row0 = blockIdx.y * 64, col0 = blockIdx.x * BN;
    const int lane = t & 63, w = t >> 6;
    const int wm = w >> 1, wn = w & 1;
    const int fr = lane & 15, fq = lane >> 4;

    f32x4 acc[2][NT];
    #pragma unroll
    for (int i = 0; i < 2; ++i)
        #pragma unroll
        for (int j = 0; j < NT; ++j) acc[i][j] = (f32x4){0.f, 0.f, 0.f, 0.f};

    for (int k0 = 0; k0 < K; k0 += 32) {
        {   // stage A (f32 -> hi/lo bf16)
            const int r = t >> 2, c = (t & 3) * 8;
            const float* ap = &A[(size_t)(row0 + r)*K + k0 + c];
            const float4 v0 = ((const float4*)ap)[0], v1 = ((const float4*)ap)[1];
            u16x8 hv, lv;
            const float xs[8] = {v0.x, v0.y, v0.z, v0.w, v1.x, v1.y, v1.z, v1.w};
            #pragma unroll
            for (int i = 0; i < 8; ++i) {
                const unsigned short hh = f2bf(xs[i]);
                hv[i] = hh; lv[i] = f2bf(xs[i] - bf2f(hh));
            }
            *(u16x8*)&Ah[r*40 + c] = hv;
            *(u16x8*)&Al[r*40 + c] = lv;
        }
        if constexpr (BN == 64) {            // stage B (pre-split bf16)
            const int n = t >> 2, c = (t & 3) * 8;
            const size_t g = (size_t)(col0 + n)*K + k0 + c;
            *(u16x8*)&Bh[n*40 + c] = *(const u16x8*)&BTh[g];
            *(u16x8*)&Bl[n*40 + c] = *(const u16x8*)&BTl[g];
        } else {
            const int n = t >> 3, c = (t & 7) * 4;
            const size_t g = (size_t)(col0 + n)*K + k0 + c;
            *(u16x4*)&Bh[n*40 + c] = *(const u16x4*)&BTh[g];
            *(u16x4*)&Bl[n*40 + c] = *(const u16x4*)&BTl[g];
        }
        __syncthreads();
        const bf16x8 ah0 = *(const bf16x8*)&Ah[(wm*32 + fr)*40 + fq*8];
        const bf16x8 ah1 = *(const bf16x8*)&Ah[(wm*32 + 16 + fr)*40 + fq*8];
        const bf16x8 al0 = *(const bf16x8*)&Al[(wm*32 + fr)*40 + fq*8];
        const bf16x8 al1 = *(const bf16x8*)&Al[(wm*32 + 16 + fr)*40 + fq*8];
        #pragma unroll
        for (int nt = 0; nt < NT; ++nt) {
            const int nb = (wn*(BN/2) + nt*16 + fr)*40 + fq*8;
            const bf16x8 bh = *(const bf16x8*)&Bh[nb];
            const bf16x8 bl = *(const bf16x8*)&Bl[nb];
            acc[0][nt] = __builtin_amdgcn_mfma_f32_16x16x32_bf16(ah0, bh, acc[0][nt], 0, 0, 0);
            acc[0][nt] = __builtin_amdgcn_mfma_f32_16x16x32_bf16(ah0, bl, acc[0][nt], 0, 0, 0);
            acc[0][nt] = __builtin_amdgcn_mfma_f32_16x16x32_bf16(al0, bh, acc[0][nt], 0, 0, 0);
            acc[1][nt] = __builtin_amdgcn_mfma_f32_16x16x32_bf16(ah1, bh, acc[1][nt], 0, 0, 0);
            acc[1][nt] = __builtin_amdgcn_mfma_f32_16x16x32_bf16(ah1, bl, acc[1][nt], 0, 0, 0);
            acc[1][nt] = __builtin_amdgcn_mfma_f32_16x16x32_bf16(al1, bh, acc[1][nt], 0, 0, 0);
        }
        __syncthreads();
    }
    #pragma unroll
    for (int mt = 0; mt < 2; ++mt) {
        #pragma unroll
        for (int nt = 0; nt < NT; ++nt) {
            const int gcol = col0 + wn*(BN/2) + nt*16 + fr;
            const float bv = bias ? bias[gcol] : 0.f;
            #pragma unroll
            for (int r = 0; r < 4; ++r) {
                const int grow = row0 + wm*32 + mt*16 + fq*4 + r;
                float v = acc[mt][nt][r] + bv;
                if (resid) v += resid[(size_t)grow*N + gcol];
                if (RELU)  v = fmaxf(v, 0.f);
                C[(size_t)grow*N + gcol] = v;
            }
        }
    }
}

// ---------------- Rcc[p] = relu(sum of 4 segments of Tn[p]) ---------------------------
__global__ void rcc_kernel(const float* __restrict__ Tn, float* __restrict__ Rcc)
{
    const int p = blockIdx.x, t = threadIdx.x;
    const float v = Tn[(size_t)p*1024 + t] + Tn[(size_t)p*1024 + 256 + t]
                  + Tn[(size_t)p*1024 + 512 + t] + Tn[(size_t)p*1024 + 768 + t];
    Rcc[p*DD + t] = fmaxf(v, 0.f);
}

// ---------------- qr[row,h,e] = sum_d (Q[row,h*32+d]+vb[h*32+d]) * WrT[h*32+d][e] -----
__global__ __launch_bounds__(256) void qr_v2(const float* __restrict__ qkvb, const float* __restrict__ vb,
                      const float* __restrict__ WrT, float* __restrict__ qr)
{
    __shared__ float qv[4][256];
    const int t = threadIdx.x, row0 = blockIdx.x * 4;
    #pragma unroll
    for (int r = 0; r < 4; ++r) qv[r][t] = qkvb[(row0+r)*768 + t] + vb[t];
    __syncthreads();
    #pragma unroll
    for (int h = 0; h < NH; ++h) {
        float acc[4] = {0.f, 0.f, 0.f, 0.f};
        const float* wt = WrT + (h*32)*DD;
        for (int d = 0; d < 32; ++d) {
            float w = wt[d*DD + t];
            #pragma unroll
            for (int r = 0; r < 4; ++r) acc[r] += qv[r][h*32 + d] * w;
        }
        #pragma unroll
        for (int r = 0; r < 4; ++r) qr[((row0+r)*NH + h)*DD + t] = acc[r];
    }
}

// ---------------- fused attention per (b,q) -------------------------------------------
__global__ __launch_bounds__(256) void attn_v2(
    const float* __restrict__ qkvb, const float* __restrict__ qr,
    const float* __restrict__ Tn, const float* __restrict__ Rcc,
    const int* __restrict__ pos_s, const int* __restrict__ pos_e,
    const int* __restrict__ seq_len, const int* __restrict__ lex_num,
    const float* __restrict__ u, float* __restrict__ obuf)
{
    __shared__ float relb[32][260];
    __shared__ float qrl[NH][260];
    __shared__ float qu[256];
    __shared__ float sc[NH][260];
    __shared__ float redbuf[2048];
    const int t = threadIdx.x;
    const int row = blockIdx.x;
    const int b = row >> 8, q = row & 255;
    const int totlen = seq_len[b] + lex_num[b];
    if (q >= SS && q >= totlen) {
        obuf[row*DD + t] = 0.f;
        return;
    }
    qu[t] = qkvb[row*768 + t] + u[t];
    #pragma unroll
    for (int h = 0; h < NH; ++h) qrl[h][t] = qr[(row*NH + h)*DD + t];
    const int ps_q = pos_s[row], pe_q = pos_e[row];
    const int* psb = pos_s + b*LT;
    const int* peb = pos_e + b*LT;
    const bool qchar = (q < SS);
    const int br = t >> 3, bc4 = (t & 7)*4;
    const int dk = t & 31, seg = t >> 5;

    for (int K0 = 0; K0 < totlen; K0 += 32) {
        __syncthreads();
        {
            const int kg = K0 + br;
            const int sk = psb[kg], ek = peb[kg];
            if (qchar && kg < SS) {
                const float* rp = Rcc + (ps_q - sk + 512)*DD;
                #pragma unroll
                for (int i = 0; i < 8; ++i) {
                    int e = i*32 + bc4;
                    *(float4*)&relb[br][e] = *(const float4*)&rp[e];
                }
            } else {
                const float* t0 = Tn + (size_t)(ps_q - sk + 512)*1024;
                const float* t1 = Tn + (size_t)(ps_q - ek + 512)*1024 + 256;
                const float* t2 = Tn + (size_t)(pe_q - sk + 512)*1024 + 512;
                const float* t3 = Tn + (size_t)(pe_q - ek + 512)*1024 + 768;
                #pragma unroll
                for (int i = 0; i < 8; ++i) {
                    int e = i*32 + bc4;
                    float4 a = *(const float4*)&t0[e];
                    float4 bb = *(const float4*)&t1[e];
                    float4 c = *(const float4*)&t2[e];
                    float4 d = *(const float4*)&t3[e];
                    float4 v;
                    v.x = fmaxf(a.x + bb.x + c.x + d.x, 0.f);
                    v.y = fmaxf(a.y + bb.y + c.y + d.y, 0.f);
                    v.z = fmaxf(a.z + bb.z + c.z + d.z, 0.f);
                    v.w = fmaxf(a.w + bb.w + c.w + d.w, 0.f);
                    *(float4*)&relb[br][e] = v;
                }
            }
        }
        __syncthreads();
        {
            float a[8] = {0.f,0.f,0.f,0.f,0.f,0.f,0.f,0.f};
            const int e0 = seg*32;
            #pragma unroll
            for (int e4 = 0; e4 < 8; ++e4) {
                float4 r4 = *(const float4*)&relb[dk][e0 + e4*4];
                #pragma unroll
                for (int h = 0; h < 8; ++h) {
                    float4 q4 = *(const float4*)&qrl[h][e0 + e4*4];
                    a[h] += r4.x*q4.x + r4.y*q4.y + r4.z*q4.z + r4.w*q4.w;
                }
            }
            {
                const float* kp = qkvb + (size_t)(b*LT + K0 + dk)*768 + 256 + seg*32;
                float acv = 0.f;
                #pragma unroll
                for (int d4 = 0; d4 < 8; ++d4) {
                    float4 kv = *(const float4*)&kp[d4*4];
                    float4 qv = *(const float4*)&qu[seg*32 + d4*4];
                    acv += kv.x*qv.x + kv.y*qv.y + kv.z*qv.z + kv.w*qv.w;
                }
                a[seg] += acv;
            }
            float4* rb = (float4*)&redbuf[(seg*32 + dk)*8];
            rb[0] = make_float4(a[0], a[1], a[2], a[3]);
            rb[1] = make_float4(a[4], a[5], a[6], a[7]);
        }
        __syncthreads();
        {
            const int k = t >> 3, h = t & 7;
            float s = 0.f;
            #pragma unroll
            for (int g = 0; g < 8; ++g) s += redbuf[g*256 + t];
            s *= 0.17677669529663687f;
            const int kg = K0 + k;
            if (kg >= totlen) s = NEGINF;
            sc[h][kg] = s;
        }
    }
    __syncthreads();
    {
        const int g = t >> 5, lane = t & 31;
        float vals[8];
        float m = -INFINITY;
        #pragma unroll
        for (int i = 0; i < 8; ++i) {
            int kidx = lane + 32*i;
            vals[i] = (kidx < totlen) ? sc[g][kidx] : NEGINF;
            m = fmaxf(m, vals[i]);
        }
        #pragma unroll
        for (int off = 16; off >= 1; off >>= 1) m = fmaxf(m, __shfl_xor(m, off, 32));
        float sum = 0.f;
        #pragma unroll
        for (int i = 0; i < 8; ++i) { vals[i] = expf(vals[i] - m); sum += vals[i]; }
        #pragma unroll
        for (int off = 16; off >= 1; off >>= 1) sum += __shfl_xor(sum, off, 32);
        const float inv = 1.0f / sum;
        #pragma unroll
        for (int i = 0; i < 8; ++i) sc[g][lane + 32*i] = vals[i] * inv;
    }
    __syncthreads();
    {
        const int j4 = (t & 63)*4, kr = t >> 6;
        const int h = j4 >> 5;
        float4 acc = make_float4(0.f, 0.f, 0.f, 0.f);
        const float* vp = qkvb + (size_t)(b*LT)*768 + 512 + j4;
        for (int k = kr; k < totlen; k += 4) {
            const float p = sc[h][k];
            float4 v = *(const float4*)&vp[(size_t)k*768];
            acc.x += p*v.x; acc.y += p*v.y; acc.z += p*v.z; acc.w += p*v.w;
        }
        *(float4*)&redbuf[kr*256 + j4] = acc;
    }
    __syncthreads();
    obuf[row*DD + t] = redbuf[t] + redbuf[256 + t] + redbuf[512 + t] + redbuf[768 + t];
}

// ---------------- LayerNorm over last dim (256) ---------------------------------------
__global__ void ln_kernel(const float* __restrict__ in, const float* __restrict__ g,
                          const float* __restrict__ bb, float* __restrict__ out)
{
    __shared__ float red[4];
    const int t = threadIdx.x, row = blockIdx.x;
    float v = in[row*DD + t];
    float s = v;
    #pragma unroll
    for (int off = 32; off >= 1; off >>= 1) s += __shfl_xor(s, off, 64);
    if ((t & 63) == 0) red[t >> 6] = s;
    __syncthreads();
    float m = (red[0] + red[1] + red[2] + red[3]) * (1.0f/256.0f);
    __syncthreads();
    float d = v - m;
    float s2 = d*d;
    #pragma unroll
    for (int off = 32; off >= 1; off >>= 1) s2 += __shfl_xor(s2, off, 64);
    if ((t & 63) == 0) red[t >> 6] = s2;
    __syncthreads();
    float var = (red[0] + red[1] + red[2] + red[3]) * (1.0f/256.0f);
    out[row*DD + t] = d * rsqrtf(var + 1e-5f) * g[t] + bb[t];
}

// ---------------- final: logits[b,s] = x[b,s] @ Wout + bout ---------------------------
__global__ void out_kernel(const float* __restrict__ x, const float* __restrict__ Wout,
                           const float* __restrict__ bout, float* __restrict__ out)
{
    __shared__ float xs[256];
    const int t = threadIdx.x, row = blockIdx.x;
    const int b = row / SS, s = row % SS;
    const float* xr = x + (b*LT + s)*DD;
    for (int i = t; i < DD; i += 64) xs[i] = xr[i];
    __syncthreads();
    if (t < 20) {
        float acc = bout[t];
        for (int d = 0; d < DD; ++d) acc += xs[d] * Wout[d*20 + t];
        out[row*20 + t] = acc;
    }
}

extern "C" void kernel_launch(void* const* d_in, const int* in_sizes, int n_in,
                              void* d_out, int out_size, void* d_ws, size_t ws_size,
                              hipStream_t stream)
{
    const int*   lattice = (const int*)d_in[0];
    const int*   bigrams = (const int*)d_in[1];
    const int*   seq_len = (const int*)d_in[2];
    const int*   lex_num = (const int*)d_in[3];
    const int*   pos_s   = (const int*)d_in[4];
    const int*   pos_e   = (const int*)d_in[5];
    const float* bert    = (const float*)d_in[7];
    const float* lat_t   = (const float*)d_in[8];
    const float* big_t   = (const float*)d_in[9];
    const float* Wc      = (const float*)d_in[10];
    const float* bc      = (const float*)d_in[11];
    const float* Wl      = (const float*)d_in[12];
    const float* bl      = (const float*)d_in[13];
    const float* W_fus   = (const float*)d_in[14];
    const float* b_fus   = (const float*)d_in[15];
    const float* Wq      = (const float*)d_in[16];
    const float* bq      = (const float*)d_in[17];
    const float* Wk      = (const float*)d_in[18];
    const float* bk      = (const float*)d_in[19];
    const float* Wv      = (const float*)d_in[20];
    const float* bv      = (const float*)d_in[21];
    const float* Wr      = (const float*)d_in[22];
    /* d_in[23] br: dropped — constant over k, softmax shift-invariant */
    const float* u_bias  = (const float*)d_in[24];
    const float* v_bias  = (const float*)d_in[25];
    const float* Wo      = (const float*)d_in[26];
    const float* bo      = (const float*)d_in[27];
    const float* ln1g    = (const float*)d_in[28];
    const float* ln1b    = (const float*)d_in[29];
    const float* W1      = (const float*)d_in[30];
    const float* b1      = (const float*)d_in[31];
    const float* W2      = (const float*)d_in[32];
    const float* b2      = (const float*)d_in[33];
    const float* ln2g    = (const float*)d_in[34];
    const float* ln2b    = (const float*)d_in[35];
    const float* Wout    = (const float*)d_in[36];
    const float* bout    = (const float*)d_in[37];

    float* ws = (float*)d_ws;
    float* qkvb = ws;  ws += NB*LT*768;
    float* ob   = ws;  ws += NB*LT*DD;
    float* t1   = ws;  ws += NB*LT*DD;
    float* x2   = ws;  ws += NB*LT*DD;
    float* t2   = ws;  ws += NB*LT*DD;
    float* hb   = ws;  ws += NB*LT*FFD;
    float* x    = ws;  ws += NB*LT*DD;
    float* Tn   = ws;  ws += 1088*1024;
    float* Rcc  = ws;  ws += 1025*DD;
    float* WrT  = ws;  ws += NLAYER*DD*DD;
    float* qr   = ws;  ws += NB*LT*NH*DD;
    float* PEf  = ws;  ws += 1088*DD;
    float* Wcomb= ws;  ws += KG*DD;
    float* bqkv = ws;  ws += NLAYER*768;
    float* bfus4= ws;  ws += 1024;
    unsigned short* us = (unsigned short*)ws;
    unsigned short* WcombT_h = us; us += 256*KG;
    unsigned short* WcombT_l = us; us += 256*KG;
    unsigned short* WqkvT_h  = us; us += NLAYER*768*256;
    unsigned short* WqkvT_l  = us; us += NLAYER*768*256;
    unsigned short* WoT_h    = us; us += NLAYER*256*256;
    unsigned short* WoT_l    = us; us += NLAYER*256*256;
    unsigned short* W1T_h    = us; us += NLAYER*1024*256;
    unsigned short* W1T_l    = us; us += NLAYER*1024*256;
    unsigned short* W2T_h    = us; us += NLAYER*256*1024;
    unsigned short* W2T_l    = us; us += NLAYER*256*1024;
    unsigned short* WfusT_h  = us; us += 1024*256;
    unsigned short* WfusT_l  = us; us += 1024*256;
    float* G = qkvb;   // alias: G[1024][992] spans qkvb+ob, dead before QKV gemm

    const int M = NB*LT;

    gather_kernel<<<M, 256, 0, stream>>>(lattice, bigrams, seq_len, lex_num,
                                         bert, lat_t, big_t, G);
    wcomb_kernel<<<KG, 256, 0, stream>>>(Wc, bc, Wl, bl, Wcomb);
    pe_kernel<<<1088, 256, 0, stream>>>(PEf);
    smallpack<<<1, 256, 0, stream>>>(bq, bk, bv, b_fus, bqkv, bfus4);
    transpose_wr<<<NLAYER*DD, 256, 0, stream>>>(Wr, WrT);
    trans_all<<<dim3(256, 6, 6), 256, 0, stream>>>(Wcomb, Wq, Wk, Wv, Wo, W1, W2, W_fus,
        WcombT_h, WcombT_l, WqkvT_h, WqkvT_l, WoT_h, WoT_l,
        W1T_h, W1T_l, W2T_h, W2T_l, WfusT_h, WfusT_l);

    // T = PE @ W_fus (4 tables as column segments) + bfus4
    gemm_bt_mfma<64,false><<<dim3(1024/64, 1088/64), 256, 0, stream>>>(
        PEf, WfusT_h, WfusT_l, bfus4, nullptr, Tn, 1088, 1024, 256);
    rcc_kernel<<<1025, 256, 0, stream>>>(Tn, Rcc);

    // embed: x = G @ Wcomb (masks+biases folded)
    gemm_bt_mfma<32,false><<<dim3(DD/32, M/64), 256, 0, stream>>>(
        G, WcombT_h, WcombT_l, nullptr, nullptr, x, M, DD, KG);

    for (int l = 0; l < NLAYER; ++l) {
        gemm_bt_mfma<64,false><<<dim3(768/64, M/64), 256, 0, stream>>>(
            x, WqkvT_h + l*768*256, WqkvT_l + l*768*256, bqkv + l*768, nullptr, qkvb, M, 768, DD);
        qr_v2<<<M/4, 256, 0, stream>>>(qkvb, v_bias + l*DD, WrT + l*DD*DD, qr);
        attn_v2<<<M, 256, 0, stream>>>(qkvb, qr, Tn, Rcc, pos_s, pos_e,
                                       seq_len, lex_num, u_bias + l*DD, ob);
        gemm_bt_mfma<32,false><<<dim3(DD/32, M/64), 256, 0, stream>>>(
            ob, WoT_h + l*65536, WoT_l + l*65536, bo + l*DD, x, t1, M, DD, DD);
        ln_kernel<<<M, 256, 0, stream>>>(t1, ln1g + l*DD, ln1b + l*DD, x2);
        gemm_bt_mfma<64,true><<<dim3(FFD/64, M/64), 256, 0, stream>>>(
            x2, W1T_h + l*262144, W1T_l + l*262144, b1 + l*FFD, nullptr, hb, M, FFD, DD);
        gemm_bt_mfma<32,false><<<dim3(DD/32, M/64), 256, 0, stream>>>(
            hb, W2T_h + l*262144, W2T_l + l*262144, b2 + l*DD, x2, t2, M, DD, FFD);
        ln_kernel<<<M, 256, 0, stream>>>(t2, ln2g + l*DD, ln2b + l*DD, x);
    }
    out_kernel<<<NB*SS, 64, 0, stream>>>(x, Wout, bout, (float*)d_out);
}